// Round 7
// baseline (233.017 us; speedup 1.0000x reference)
//
#include <hip/hip_runtime.h>

#define S 2048
#define DIM 2048
#define H 32
#define NP 768    // 256(q) + 256(k) + 256(v) columns (gate moved out)

using u16 = unsigned short;
using short8 = __attribute__((ext_vector_type(8))) short;
using f32x4 = __attribute__((ext_vector_type(4))) float;

__device__ __forceinline__ u16 f2bf(float x) {
  union { float f; unsigned u; } v; v.f = x;
  unsigned r = v.u + 0x7fffu + ((v.u >> 16) & 1u);
  return (u16)(r >> 16);
}
__device__ __forceinline__ float sigm(float x) { return 1.f / (1.f + __expf(-x)); }

// async global->LDS, 16B per lane; LDS dest must be wave-uniform base + lane*16
#define GLOAD_LDS16(g, l)                                                      \
  __builtin_amdgcn_global_load_lds(                                            \
      (const __attribute__((address_space(1))) unsigned*)(g),                  \
      (__attribute__((address_space(3))) unsigned*)(l), 16, 0, 0)

// ---- prep: fp32 -> bf16 elementwise (hs) ----
__global__ void f32_to_bf16_k(const float* __restrict__ in, u16* __restrict__ out) {
  int i = (blockIdx.x * 256 + threadIdx.x) * 8;
  float4 a = *(const float4*)(in + i);
  float4 b = *(const float4*)(in + i + 4);
  uint4 r;
  r.x = f2bf(a.x) | ((unsigned)f2bf(a.y) << 16);
  r.y = f2bf(a.z) | ((unsigned)f2bf(a.w) << 16);
  r.z = f2bf(b.x) | ((unsigned)f2bf(b.y) << 16);
  r.w = f2bf(b.z) | ((unsigned)f2bf(b.w) << 16);
  *(uint4*)(out + i) = r;
}

// ---- prep: transpose fp32 [K x N] -> bf16 [N x K] ----
__global__ void transpose_bf16_k(const float* __restrict__ in, u16* __restrict__ out,
                                 int K, int N) {
  __shared__ float tile[32][33];
  int nb = blockIdx.x * 32, kb = blockIdx.y * 32;
  int tx = threadIdx.x, ty = threadIdx.y;
  for (int r = ty; r < 32; r += 8)
    tile[r][tx] = in[(size_t)(kb + r) * N + nb + tx];
  __syncthreads();
  for (int r = ty; r < 32; r += 8)
    out[(size_t)(nb + r) * K + kb + tx] = f2bf(tile[tx][r]);
}

// ---- GEMM1': P = hs@[Wq|Wk|Wv] raw logits. 128x64 tile, dbuf global_load_lds ----
__global__ __launch_bounds__(256)
void gemm_proj_k(const u16* __restrict__ A, const u16* __restrict__ Bt,
                 float* __restrict__ C, int K, int ldc) {
  __shared__ u16 As[2][128][32];
  __shared__ u16 Bs[2][64][32];
  const int t = threadIdx.x;
  const int bm = blockIdx.y * 128, bn = blockIdx.x * 64;
  const int wave = t >> 6, lane = t & 63;
  const int wm = (wave >> 1) * 64, wn = (wave & 1) * 32;
  const int l16 = lane & 15, quad = lane >> 4;
  const int srow = t >> 2, scol = (t & 3) * 8;
  const u16* Ap = A + (size_t)(bm + srow) * K + scol;
  const u16* Bp = Bt + (size_t)(bn + srow) * K + scol;
  f32x4 acc[4][2];
#pragma unroll
  for (int i = 0; i < 4; i++)
#pragma unroll
    for (int j = 0; j < 2; j++) acc[i][j] = (f32x4){0.f, 0.f, 0.f, 0.f};
  GLOAD_LDS16(Ap, &As[0][srow][scol]);
  GLOAD_LDS16(Ap + (size_t)64 * K, &As[0][srow + 64][scol]);
  GLOAD_LDS16(Bp, &Bs[0][srow][scol]);
  for (int kk = 0; kk < K; kk += 32) {
    const int cur = (kk >> 5) & 1, nxt = cur ^ 1;
    __syncthreads();
    if (kk + 32 < K) {
      GLOAD_LDS16(Ap + kk + 32, &As[nxt][srow][scol]);
      GLOAD_LDS16(Ap + (size_t)64 * K + kk + 32, &As[nxt][srow + 64][scol]);
      GLOAD_LDS16(Bp + kk + 32, &Bs[nxt][srow][scol]);
    }
    short8 af[4], bf[2];
#pragma unroll
    for (int mt = 0; mt < 4; mt++) af[mt] = *(const short8*)&As[cur][wm + mt * 16 + l16][quad * 8];
#pragma unroll
    for (int nt = 0; nt < 2; nt++) bf[nt] = *(const short8*)&Bs[cur][wn + nt * 16 + l16][quad * 8];
#pragma unroll
    for (int mt = 0; mt < 4; mt++)
#pragma unroll
      for (int nt = 0; nt < 2; nt++)
        acc[mt][nt] = __builtin_amdgcn_mfma_f32_16x16x32_bf16(af[mt], bf[nt], acc[mt][nt], 0, 0, 0);
  }
  // C/D layout: col = lane&15, row = quad*4 + reg  [verified m89]
#pragma unroll
  for (int mt = 0; mt < 4; mt++)
#pragma unroll
    for (int nt = 0; nt < 2; nt++)
#pragma unroll
      for (int r = 0; r < 4; r++) {
        int m = bm + wm + mt * 16 + quad * 4 + r;
        int n = bn + wn + nt * 16 + l16;
        C[(size_t)m * ldc + n] = acc[mt][nt][r];
      }
}

// ---- out = (O2@Wot) * sigmoid(hs@Wg): 64x64 tile, two dbuf K-phases ----
__global__ __launch_bounds__(256)
void gemm_outgate_k(const u16* __restrict__ O2, const u16* __restrict__ Wot,
                    const u16* __restrict__ hsb, const u16* __restrict__ Wgt,
                    float* __restrict__ out) {
  __shared__ u16 As[2][64][32];
  __shared__ u16 Bs[2][64][32];
  const int t = threadIdx.x;
  const int bm = blockIdx.y * 64, bn = blockIdx.x * 64;
  const int wave = t >> 6, lane = t & 63;
  const int wm = (wave >> 1) * 32, wn = (wave & 1) * 32;
  const int l16 = lane & 15, quad = lane >> 4;
  const int srow = t >> 2, scol = (t & 3) * 8;
  const u16* Ap1 = O2 + (size_t)(bm + srow) * 256 + scol;
  const u16* Bp1 = Wot + (size_t)(bn + srow) * 256 + scol;
  const u16* Ap2 = hsb + (size_t)(bm + srow) * 2048 + scol;
  const u16* Bp2 = Wgt + (size_t)(bn + srow) * 2048 + scol;
  f32x4 acc1[2][2], acc2[2][2];
#pragma unroll
  for (int i = 0; i < 2; i++)
#pragma unroll
    for (int j = 0; j < 2; j++) {
      acc1[i][j] = (f32x4){0.f, 0.f, 0.f, 0.f};
      acc2[i][j] = (f32x4){0.f, 0.f, 0.f, 0.f};
    }
  GLOAD_LDS16(Ap1, &As[0][srow][scol]);
  GLOAD_LDS16(Bp1, &Bs[0][srow][scol]);
  // phase 1: K=256 over O2/Wot -> acc1
  for (int kk = 0; kk < 256; kk += 32) {
    const int cur = (kk >> 5) & 1, nxt = cur ^ 1;
    __syncthreads();
    if (kk + 32 < 256) {
      GLOAD_LDS16(Ap1 + kk + 32, &As[nxt][srow][scol]);
      GLOAD_LDS16(Bp1 + kk + 32, &Bs[nxt][srow][scol]);
    } else {  // bridge: prefetch phase-2 tile 0
      GLOAD_LDS16(Ap2, &As[nxt][srow][scol]);
      GLOAD_LDS16(Bp2, &Bs[nxt][srow][scol]);
    }
    short8 af[2], bf[2];
#pragma unroll
    for (int mt = 0; mt < 2; mt++) af[mt] = *(const short8*)&As[cur][wm + mt * 16 + l16][quad * 8];
#pragma unroll
    for (int nt = 0; nt < 2; nt++) bf[nt] = *(const short8*)&Bs[cur][wn + nt * 16 + l16][quad * 8];
#pragma unroll
    for (int mt = 0; mt < 2; mt++)
#pragma unroll
      for (int nt = 0; nt < 2; nt++)
        acc1[mt][nt] = __builtin_amdgcn_mfma_f32_16x16x32_bf16(af[mt], bf[nt], acc1[mt][nt], 0, 0, 0);
  }
  // phase 2: K=2048 over hs/Wgt -> acc2 (gate logits); buf parity continues (8 even)
  for (int kk = 0; kk < 2048; kk += 32) {
    const int cur = (kk >> 5) & 1, nxt = cur ^ 1;
    __syncthreads();
    if (kk + 32 < 2048) {
      GLOAD_LDS16(Ap2 + kk + 32, &As[nxt][srow][scol]);
      GLOAD_LDS16(Bp2 + kk + 32, &Bs[nxt][srow][scol]);
    }
    short8 af[2], bf[2];
#pragma unroll
    for (int mt = 0; mt < 2; mt++) af[mt] = *(const short8*)&As[cur][wm + mt * 16 + l16][quad * 8];
#pragma unroll
    for (int nt = 0; nt < 2; nt++) bf[nt] = *(const short8*)&Bs[cur][wn + nt * 16 + l16][quad * 8];
#pragma unroll
    for (int mt = 0; mt < 2; mt++)
#pragma unroll
      for (int nt = 0; nt < 2; nt++)
        acc2[mt][nt] = __builtin_amdgcn_mfma_f32_16x16x32_bf16(af[mt], bf[nt], acc2[mt][nt], 0, 0, 0);
  }
#pragma unroll
  for (int mt = 0; mt < 2; mt++)
#pragma unroll
    for (int nt = 0; nt < 2; nt++)
#pragma unroll
      for (int r = 0; r < 4; r++) {
        int m = bm + wm + mt * 16 + quad * 4 + r;
        int n = bn + wn + nt * 16 + l16;
        out[(size_t)m * DIM + n] = acc1[mt][nt][r] * sigm(acc2[mt][nt][r]);
      }
}

// ---- MFMA attention partials: block = (head, q-tile 128, k-chunk 256) ----
// P holds raw logits; sigmoid applied during staging (same fp32 math as before).
// S^T scores: A=Pk (m=key), B=Pq (n=q) -> C row=key(quad*4+r), col=q(l16).
// e = exp2(dot*2/ln2 - sk*log2e); exp(-sq) cancels in o/l.
// PV: A = P (m=q), B = V^T rows (n=dim, row 8 = ones -> l in output col 8).
// P_lds XOR swizzle blk' = (col>>3) ^ ((row>>1)&7): 2-way (free) on write b64 + read b128.
__global__ __launch_bounds__(256)
void attn_mfma_k(const float* __restrict__ P, float* __restrict__ Part) {
  __shared__ u16 Plds[128 * 128];     // swizzled bf16 P slab [q 0..127][k-slab 0..127]
  __shared__ u16 Vt[16 * 264];        // V^T [dim 0..15][key 0..255], row8=1, rows9-15=0
  __shared__ u16 Klds[256 * 8];       // Pk bf16 [key][bit]
  __shared__ u16 Qlds[128 * 8];       // Pq bf16 [q][bit]
  __shared__ float sk2[256];          // sum(pk)*log2(e)
  const int h = blockIdx.y;
  int tau = blockIdx.x, m = 0;
  while (tau >= (m >> 1) + 1) { tau -= (m >> 1) + 1; m++; }
  const int kc = tau;
  const bool needMask = (kc == (m >> 1));
  const int q0 = m * 128, kb = kc * 256;
  const int t = threadIdx.x, wave = t >> 6, lane = t & 63;
  const int l16 = lane & 15, quad = lane >> 4;
  // ---- stage (sigmoid on the fly) ----
  if (t < 128) {
    const float* rq = P + (size_t)(q0 + t) * NP + h * 8;
    float4 a = *(const float4*)rq, b = *(const float4*)(rq + 4);
    uint4 w;
    w.x = f2bf(sigm(a.x)) | ((unsigned)f2bf(sigm(a.y)) << 16);
    w.y = f2bf(sigm(a.z)) | ((unsigned)f2bf(sigm(a.w)) << 16);
    w.z = f2bf(sigm(b.x)) | ((unsigned)f2bf(sigm(b.y)) << 16);
    w.w = f2bf(sigm(b.z)) | ((unsigned)f2bf(sigm(b.w)) << 16);
    *(uint4*)&Qlds[t * 8] = w;
  }
  {
    const float* rk = P + (size_t)(kb + t) * NP + 256 + h * 8;
    float4 k0 = *(const float4*)rk, k1 = *(const float4*)(rk + 4);
    float4 v0 = *(const float4*)(rk + 256), v1 = *(const float4*)(rk + 260);
    k0.x = sigm(k0.x); k0.y = sigm(k0.y); k0.z = sigm(k0.z); k0.w = sigm(k0.w);
    k1.x = sigm(k1.x); k1.y = sigm(k1.y); k1.z = sigm(k1.z); k1.w = sigm(k1.w);
    sk2[t] = (k0.x + k0.y + k0.z + k0.w + k1.x + k1.y + k1.z + k1.w) * 1.44269504f;
    uint4 w;
    w.x = f2bf(k0.x) | ((unsigned)f2bf(k0.y) << 16);
    w.y = f2bf(k0.z) | ((unsigned)f2bf(k0.w) << 16);
    w.z = f2bf(k1.x) | ((unsigned)f2bf(k1.y) << 16);
    w.w = f2bf(k1.z) | ((unsigned)f2bf(k1.w) << 16);
    *(uint4*)&Klds[t * 8] = w;
    Vt[0 * 264 + t] = f2bf(sigm(v0.x)); Vt[1 * 264 + t] = f2bf(sigm(v0.y));
    Vt[2 * 264 + t] = f2bf(sigm(v0.z)); Vt[3 * 264 + t] = f2bf(sigm(v0.w));
    Vt[4 * 264 + t] = f2bf(sigm(v1.x)); Vt[5 * 264 + t] = f2bf(sigm(v1.y));
    Vt[6 * 264 + t] = f2bf(sigm(v1.z)); Vt[7 * 264 + t] = f2bf(sigm(v1.w));
    Vt[8 * 264 + t] = 0x3F80;   // 1.0 bf16 -> row sums (l) in output col 8
#pragma unroll
    for (int d = 9; d < 16; d++) Vt[d * 264 + t] = 0;
  }
  __syncthreads();
  // ---- B-frags (Pq), fixed per wave's two q-tiles ----
  short8 bq[2];
#pragma unroll
  for (int i = 0; i < 2; i++) {
    short8 z = {0, 0, 0, 0, 0, 0, 0, 0};
    if (quad == 0) z = *(const short8*)&Qlds[((wave * 2 + i) * 16 + l16) * 8];
    bq[i] = z;
  }
  f32x4 O[2];
  O[0] = (f32x4){0.f, 0.f, 0.f, 0.f};
  O[1] = (f32x4){0.f, 0.f, 0.f, 0.f};
  const int nsl = needMask ? (m & 1) + 1 : 2;
  const int swz = (l16 >> 1) & 7;   // row-derived XOR for this lane's q-rows / write rows
  for (int sl = 0; sl < nsl; sl++) {
    const int ks = sl * 128;
    const bool dm = needMask && (sl == (m & 1));
    // ---- scores + exp -> P_lds ----
    for (int kt = 0; kt < 8; kt++) {
      short8 ak = {0, 0, 0, 0, 0, 0, 0, 0};
      if (quad == 0) ak = *(const short8*)&Klds[(ks + kt * 16 + l16) * 8];
      float4 s2 = *(const float4*)&sk2[ks + kt * 16 + quad * 4];
#pragma unroll
      for (int i = 0; i < 2; i++) {
        f32x4 c = __builtin_amdgcn_mfma_f32_16x16x32_bf16(
            ak, bq[i], (f32x4){0.f, 0.f, 0.f, 0.f}, 0, 0, 0);
        float e0 = exp2f(c[0] * 2.88539008f - s2.x);
        float e1 = exp2f(c[1] * 2.88539008f - s2.y);
        float e2 = exp2f(c[2] * 2.88539008f - s2.z);
        float e3 = exp2f(c[3] * 2.88539008f - s2.w);
        if (dm) {
          int q = q0 + (wave * 2 + i) * 16 + l16;
          int key = kb + ks + kt * 16 + quad * 4;
          e0 = (key + 0 <= q) ? e0 : 0.f;
          e1 = (key + 1 <= q) ? e1 : 0.f;
          e2 = (key + 2 <= q) ? e2 : 0.f;
          e3 = (key + 3 <= q) ? e3 : 0.f;
        }
        uint2 pk2;
        pk2.x = f2bf(e0) | ((unsigned)f2bf(e1) << 16);
        pk2.y = f2bf(e2) | ((unsigned)f2bf(e3) << 16);
        int row = (wave * 2 + i) * 16 + l16;
        int cb = 2 * kt + (quad >> 1);
        int pb = cb ^ swz;
        *(uint2*)&Plds[row * 128 + pb * 8 + (quad & 1) * 4] = pk2;
      }
    }
    // same-wave RAW on Plds rows (each wave owns its 32 q-rows) -> no barrier
    // ---- PV ----
#pragma unroll
    for (int kc4 = 0; kc4 < 4; kc4++) {
      short8 bv = *(const short8*)&Vt[l16 * 264 + ks + kc4 * 32 + quad * 8];
#pragma unroll
      for (int i = 0; i < 2; i++) {
        int row = (wave * 2 + i) * 16 + l16;
        int pb = (kc4 * 4 + quad) ^ swz;
        short8 ap = *(const short8*)&Plds[row * 128 + pb * 8];
        O[i] = __builtin_amdgcn_mfma_f32_16x16x32_bf16(ap, bv, O[i], 0, 0, 0);
      }
    }
  }
  // ---- write partials: O C-layout: row=q(quad*4+r), col=dim(l16); col8 = l ----
  if (l16 < 9) {
#pragma unroll
    for (int i = 0; i < 2; i++) {
      int qb = q0 + (wave * 2 + i) * 16 + quad * 4;
#pragma unroll
      for (int r = 0; r < 4; r++)
        Part[(((size_t)h * S + qb + r) * 8 + kc) * 12 + l16] = O[i][r];
    }
  }
}

// ---- merge partials, divide, v_emb interpolate, emit bf16 O2 [S x 256] ----
__global__ __launch_bounds__(256)
void attn_merge_k(const float* __restrict__ Part, const float* __restrict__ e0,
                  const float* __restrict__ e1, u16* __restrict__ O2) {
  const int q = blockIdx.x;
  const int t = threadIdx.x;         // t = h*8 + d
  const int d = t & 7;
  const int nch = (q >> 8) + 1;
  size_t base = ((size_t)(t >> 3) * S + q) * 8 * 12;
  float ov = 0.f, lv = 0.f;
  for (int kc = 0; kc < nch; kc++) {
    ov += Part[base + (size_t)kc * 12 + d];
    lv += Part[base + (size_t)kc * 12 + 8];
  }
  float outv = ov / lv;
  float r = e0[t] + (e1[t] - e0[t]) * outv;
  O2[(size_t)q * 256 + t] = f2bf(r);
}

extern "C" void kernel_launch(void* const* d_in, const int* in_sizes, int n_in,
                              void* d_out, int out_size, void* d_ws, size_t ws_size,
                              hipStream_t stream) {
  const float* hs = (const float*)d_in[0];
  const float* Wq = (const float*)d_in[1];
  const float* Wk = (const float*)d_in[2];
  const float* Wv = (const float*)d_in[3];
  const float* Wo = (const float*)d_in[4];
  const float* Wg = (const float*)d_in[5];
  const float* e0 = (const float*)d_in[6];
  const float* e1 = (const float*)d_in[7];
  float* out = (float*)d_out;
  char* ws = (char*)d_ws;
  // workspace layout (bytes)
  u16*   Abf  = (u16*)(ws + 0);          //  8,388,608  hs bf16 [2048 x 2048]
  u16*   Wt   = (u16*)(ws + 8388608);    // 11,534,336  [Wq|Wk|Wv|Wg]^T bf16 [2816 x 2048]
  u16*   Wot  = (u16*)(ws + 19922944);   //  1,048,576  Wo^T bf16 [2048 x 256]
  u16*   O2   = (u16*)(ws + 20971520);   //  1,048,576  attn out (emb-interp) bf16 [2048 x 256]
  float* P    = (float*)(ws + 22020096); //  6,291,456  hs@[Wq|Wk|Wv] logits fp32 [2048 x 768]
  float* Part = (float*)(ws + 28311552); // 25,165,824  partials [H][S][8 chunks][12]
  u16*   Wgt  = Wt + (size_t)768 * 2048; // gate weight transposed [2048 x 2048]

  dim3 tb(32, 8);
  f32_to_bf16_k<<<dim3((S * DIM) / (256 * 8)), 256, 0, stream>>>(hs, Abf);
  transpose_bf16_k<<<dim3(8, 64),  tb, 0, stream>>>(Wq, Wt,                      2048, 256);
  transpose_bf16_k<<<dim3(8, 64),  tb, 0, stream>>>(Wk, Wt + (size_t)256 * 2048, 2048, 256);
  transpose_bf16_k<<<dim3(8, 64),  tb, 0, stream>>>(Wv, Wt + (size_t)512 * 2048, 2048, 256);
  transpose_bf16_k<<<dim3(64, 64), tb, 0, stream>>>(Wg, Wgt, 2048, 2048);
  transpose_bf16_k<<<dim3(64, 8),  tb, 0, stream>>>(Wo, Wot, 256, 2048);
  gemm_proj_k<<<dim3(NP / 64, S / 128), 256, 0, stream>>>(Abf, Wt, P, 2048, NP);
  attn_mfma_k<<<dim3(72, H), 256, 0, stream>>>(P, Part);
  attn_merge_k<<<dim3(S), 256, 0, stream>>>(Part, e0, e1, O2);
  gemm_outgate_k<<<dim3(DIM / 64, S / 64), 256, 0, stream>>>(O2, Wot, Abf, Wgt, out);
}

// Round 8
// 221.709 us; speedup vs baseline: 1.0510x; 1.0510x over previous
//
#include <hip/hip_runtime.h>

#define S 2048
#define DIM 2048
#define H 32
#define NP 768    // 256(q) + 256(k) + 256(v) columns (gate separate)

using u16 = unsigned short;
using short8 = __attribute__((ext_vector_type(8))) short;
using f32x4 = __attribute__((ext_vector_type(4))) float;

__device__ __forceinline__ u16 f2bf(float x) {
  union { float f; unsigned u; } v; v.f = x;
  unsigned r = v.u + 0x7fffu + ((v.u >> 16) & 1u);
  return (u16)(r >> 16);
}
__device__ __forceinline__ float sigm(float x) { return 1.f / (1.f + __expf(-x)); }

// async global->LDS, 16B per lane; LDS dest must be wave-uniform base + lane*16
#define GLOAD_LDS16(g, l)                                                      \
  __builtin_amdgcn_global_load_lds(                                            \
      (const __attribute__((address_space(1))) unsigned*)(g),                  \
      (__attribute__((address_space(3))) unsigned*)(l), 16, 0, 0)

// ---- fused prep: 5 transposes (fp32 [KxN] -> bf16 [NxK]) + hs fp32->bf16 ----
// blocks 0..127 Wq | 128..255 Wk | 256..383 Wv | 384..1407 Wg | 1408..1535 Wo
// blocks 1536..3583: hs elementwise convert (2048 elems/block)
__global__ __launch_bounds__(256)
void trans_all_k(const float* __restrict__ Wq, const float* __restrict__ Wk,
                 const float* __restrict__ Wv, const float* __restrict__ Wg,
                 const float* __restrict__ Wo, const float* __restrict__ hs,
                 u16* __restrict__ Wt, u16* __restrict__ Wot, u16* __restrict__ Abf) {
  int b = blockIdx.x;
  const int t = threadIdx.x;
  if (b >= 1536) {  // hs fp32 -> bf16, fully coalesced
    int i = ((b - 1536) * 256 + t) * 8;
    float4 a = *(const float4*)(hs + i);
    float4 c = *(const float4*)(hs + i + 4);
    uint4 r;
    r.x = f2bf(a.x) | ((unsigned)f2bf(a.y) << 16);
    r.y = f2bf(a.z) | ((unsigned)f2bf(a.w) << 16);
    r.z = f2bf(c.x) | ((unsigned)f2bf(c.y) << 16);
    r.w = f2bf(c.z) | ((unsigned)f2bf(c.w) << 16);
    *(uint4*)(Abf + i) = r;
    return;
  }
  const float* in; u16* out; int K, N;
  if (b < 384) {
    K = 2048; N = 256;
    in = (b < 128) ? Wq : (b < 256) ? Wk : Wv;
    out = Wt + (size_t)(b >> 7) * 256 * 2048;
    b &= 127;
  } else if (b < 1408) {
    in = Wg; out = Wt + (size_t)768 * 2048; K = 2048; N = 2048; b -= 384;
  } else {
    in = Wo; out = Wot; K = 256; N = 2048; b -= 1408;
  }
  const int nbN = N >> 6;
  const int kb = (b / nbN) << 6, nb = (b % nbN) << 6;
  __shared__ float tile[64][65];   // 65-stride: write-phase reads 2-way (free)
  const int n4 = (t & 15) * 4;
#pragma unroll
  for (int p = 0; p < 4; p++) {
    int k = p * 16 + (t >> 4);
    float4 v = *(const float4*)(in + (size_t)(kb + k) * N + nb + n4);
    tile[k][n4] = v.x; tile[k][n4 + 1] = v.y; tile[k][n4 + 2] = v.z; tile[k][n4 + 3] = v.w;
  }
  __syncthreads();
  const int k8 = (t & 7) * 8;
#pragma unroll
  for (int p = 0; p < 2; p++) {
    int n = p * 32 + (t >> 3);
    uint4 w;
    w.x = f2bf(tile[k8 + 0][n]) | ((unsigned)f2bf(tile[k8 + 1][n]) << 16);
    w.y = f2bf(tile[k8 + 2][n]) | ((unsigned)f2bf(tile[k8 + 3][n]) << 16);
    w.z = f2bf(tile[k8 + 4][n]) | ((unsigned)f2bf(tile[k8 + 5][n]) << 16);
    w.w = f2bf(tile[k8 + 6][n]) | ((unsigned)f2bf(tile[k8 + 7][n]) << 16);
    *(uint4*)(out + (size_t)(nb + n) * K + kb + k8) = w;
  }
}

// ---- GEMM1': P = hs@[Wq|Wk|Wv] raw logits. 128x64 tile, dbuf global_load_lds ----
__global__ __launch_bounds__(256)
void gemm_proj_k(const u16* __restrict__ A, const u16* __restrict__ Bt,
                 float* __restrict__ C, int K, int ldc) {
  __shared__ u16 As[2][128][32];
  __shared__ u16 Bs[2][64][32];
  const int t = threadIdx.x;
  const int bm = blockIdx.y * 128, bn = blockIdx.x * 64;
  const int wave = t >> 6, lane = t & 63;
  const int wm = (wave >> 1) * 64, wn = (wave & 1) * 32;
  const int l16 = lane & 15, quad = lane >> 4;
  const int srow = t >> 2, scol = (t & 3) * 8;
  const u16* Ap = A + (size_t)(bm + srow) * K + scol;
  const u16* Bp = Bt + (size_t)(bn + srow) * K + scol;
  f32x4 acc[4][2];
#pragma unroll
  for (int i = 0; i < 4; i++)
#pragma unroll
    for (int j = 0; j < 2; j++) acc[i][j] = (f32x4){0.f, 0.f, 0.f, 0.f};
  GLOAD_LDS16(Ap, &As[0][srow][scol]);
  GLOAD_LDS16(Ap + (size_t)64 * K, &As[0][srow + 64][scol]);
  GLOAD_LDS16(Bp, &Bs[0][srow][scol]);
  for (int kk = 0; kk < K; kk += 32) {
    const int cur = (kk >> 5) & 1, nxt = cur ^ 1;
    __syncthreads();
    if (kk + 32 < K) {
      GLOAD_LDS16(Ap + kk + 32, &As[nxt][srow][scol]);
      GLOAD_LDS16(Ap + (size_t)64 * K + kk + 32, &As[nxt][srow + 64][scol]);
      GLOAD_LDS16(Bp + kk + 32, &Bs[nxt][srow][scol]);
    }
    short8 af[4], bf[2];
#pragma unroll
    for (int mt = 0; mt < 4; mt++) af[mt] = *(const short8*)&As[cur][wm + mt * 16 + l16][quad * 8];
#pragma unroll
    for (int nt = 0; nt < 2; nt++) bf[nt] = *(const short8*)&Bs[cur][wn + nt * 16 + l16][quad * 8];
#pragma unroll
    for (int mt = 0; mt < 4; mt++)
#pragma unroll
      for (int nt = 0; nt < 2; nt++)
        acc[mt][nt] = __builtin_amdgcn_mfma_f32_16x16x32_bf16(af[mt], bf[nt], acc[mt][nt], 0, 0, 0);
  }
  // C/D layout: col = lane&15, row = quad*4 + reg  [verified m89]
#pragma unroll
  for (int mt = 0; mt < 4; mt++)
#pragma unroll
    for (int nt = 0; nt < 2; nt++)
#pragma unroll
      for (int r = 0; r < 4; r++) {
        int m = bm + wm + mt * 16 + quad * 4 + r;
        int n = bn + wn + nt * 16 + l16;
        C[(size_t)m * ldc + n] = acc[mt][nt][r];
      }
}

// ---- out = (O2@Wot) * sigmoid(hs@Wg): 128x128 tile, two dbuf K-phases ----
__global__ __launch_bounds__(256)
void gemm_outgate_k(const u16* __restrict__ O2, const u16* __restrict__ Wot,
                    const u16* __restrict__ hsb, const u16* __restrict__ Wgt,
                    float* __restrict__ out) {
  __shared__ u16 As[2][128][32];
  __shared__ u16 Bs[2][128][32];
  const int t = threadIdx.x;
  const int bm = blockIdx.y * 128, bn = blockIdx.x * 128;
  const int wave = t >> 6, lane = t & 63;
  const int wm = (wave >> 1) * 64, wn = (wave & 1) * 64;
  const int l16 = lane & 15, quad = lane >> 4;
  const int srow = t >> 2, scol = (t & 3) * 8;
  const u16* Ap1 = O2 + (size_t)(bm + srow) * 256 + scol;
  const u16* Bp1 = Wot + (size_t)(bn + srow) * 256 + scol;
  const u16* Ap2 = hsb + (size_t)(bm + srow) * 2048 + scol;
  const u16* Bp2 = Wgt + (size_t)(bn + srow) * 2048 + scol;
  f32x4 acc1[4][4], acc2[4][4];
#pragma unroll
  for (int i = 0; i < 4; i++)
#pragma unroll
    for (int j = 0; j < 4; j++) {
      acc1[i][j] = (f32x4){0.f, 0.f, 0.f, 0.f};
      acc2[i][j] = (f32x4){0.f, 0.f, 0.f, 0.f};
    }
  GLOAD_LDS16(Ap1, &As[0][srow][scol]);
  GLOAD_LDS16(Ap1 + (size_t)64 * 256, &As[0][srow + 64][scol]);
  GLOAD_LDS16(Bp1, &Bs[0][srow][scol]);
  GLOAD_LDS16(Bp1 + (size_t)64 * 256, &Bs[0][srow + 64][scol]);
  // phase 1: K=256 over O2/Wot -> acc1 (8 iters, even -> parity continues)
  for (int kk = 0; kk < 256; kk += 32) {
    const int cur = (kk >> 5) & 1, nxt = cur ^ 1;
    __syncthreads();
    if (kk + 32 < 256) {
      GLOAD_LDS16(Ap1 + kk + 32, &As[nxt][srow][scol]);
      GLOAD_LDS16(Ap1 + (size_t)64 * 256 + kk + 32, &As[nxt][srow + 64][scol]);
      GLOAD_LDS16(Bp1 + kk + 32, &Bs[nxt][srow][scol]);
      GLOAD_LDS16(Bp1 + (size_t)64 * 256 + kk + 32, &Bs[nxt][srow + 64][scol]);
    } else {  // bridge: prefetch phase-2 tile 0
      GLOAD_LDS16(Ap2, &As[nxt][srow][scol]);
      GLOAD_LDS16(Ap2 + (size_t)64 * 2048, &As[nxt][srow + 64][scol]);
      GLOAD_LDS16(Bp2, &Bs[nxt][srow][scol]);
      GLOAD_LDS16(Bp2 + (size_t)64 * 2048, &Bs[nxt][srow + 64][scol]);
    }
    short8 af[4], bf[4];
#pragma unroll
    for (int mt = 0; mt < 4; mt++) af[mt] = *(const short8*)&As[cur][wm + mt * 16 + l16][quad * 8];
#pragma unroll
    for (int nt = 0; nt < 4; nt++) bf[nt] = *(const short8*)&Bs[cur][wn + nt * 16 + l16][quad * 8];
#pragma unroll
    for (int mt = 0; mt < 4; mt++)
#pragma unroll
      for (int nt = 0; nt < 4; nt++)
        acc1[mt][nt] = __builtin_amdgcn_mfma_f32_16x16x32_bf16(af[mt], bf[nt], acc1[mt][nt], 0, 0, 0);
  }
  // phase 2: K=2048 over hs/Wgt -> acc2 (gate logits)
  for (int kk = 0; kk < 2048; kk += 32) {
    const int cur = (kk >> 5) & 1, nxt = cur ^ 1;
    __syncthreads();
    if (kk + 32 < 2048) {
      GLOAD_LDS16(Ap2 + kk + 32, &As[nxt][srow][scol]);
      GLOAD_LDS16(Ap2 + (size_t)64 * 2048 + kk + 32, &As[nxt][srow + 64][scol]);
      GLOAD_LDS16(Bp2 + kk + 32, &Bs[nxt][srow][scol]);
      GLOAD_LDS16(Bp2 + (size_t)64 * 2048 + kk + 32, &Bs[nxt][srow + 64][scol]);
    }
    short8 af[4], bf[4];
#pragma unroll
    for (int mt = 0; mt < 4; mt++) af[mt] = *(const short8*)&As[cur][wm + mt * 16 + l16][quad * 8];
#pragma unroll
    for (int nt = 0; nt < 4; nt++) bf[nt] = *(const short8*)&Bs[cur][wn + nt * 16 + l16][quad * 8];
#pragma unroll
    for (int mt = 0; mt < 4; mt++)
#pragma unroll
      for (int nt = 0; nt < 4; nt++)
        acc2[mt][nt] = __builtin_amdgcn_mfma_f32_16x16x32_bf16(af[mt], bf[nt], acc2[mt][nt], 0, 0, 0);
  }
#pragma unroll
  for (int mt = 0; mt < 4; mt++)
#pragma unroll
    for (int nt = 0; nt < 4; nt++)
#pragma unroll
      for (int r = 0; r < 4; r++) {
        int m = bm + wm + mt * 16 + quad * 4 + r;
        int n = bn + wn + nt * 16 + l16;
        out[(size_t)m * DIM + n] = acc1[mt][nt][r] * sigm(acc2[mt][nt][r]);
      }
}

// ---- MFMA attention partials: block = (head, q-tile 128, k-chunk 256) ----
// P holds raw logits; sigmoid applied during staging.
// S^T scores: A=Pk (m=key), B=Pq (n=q) -> C row=key(quad*4+r), col=q(l16).
// e = exp2(dot*2/ln2 - sk*log2e); exp(-sq) cancels in o/l.
// PV: A = P (m=q), B = V^T rows (n=dim, row 8 = ones -> l in output col 8).
// P_lds XOR swizzle blk' = (col>>3) ^ ((row>>1)&7): 2-way (free) on write b64 + read b128.
__global__ __launch_bounds__(256)
void attn_mfma_k(const float* __restrict__ P, float* __restrict__ Part) {
  __shared__ u16 Plds[128 * 128];     // swizzled bf16 P slab [q 0..127][k-slab 0..127]
  __shared__ u16 Vt[16 * 264];        // V^T [dim 0..15][key 0..255], row8=1, rows9-15=0
  __shared__ u16 Klds[256 * 8];       // Pk bf16 [key][bit]
  __shared__ u16 Qlds[128 * 8];       // Pq bf16 [q][bit]
  __shared__ float sk2[256];          // sum(pk)*log2(e)
  const int h = blockIdx.y;
  int tau = blockIdx.x, m = 0;
  while (tau >= (m >> 1) + 1) { tau -= (m >> 1) + 1; m++; }
  const int kc = tau;
  const bool needMask = (kc == (m >> 1));
  const int q0 = m * 128, kb = kc * 256;
  const int t = threadIdx.x, wave = t >> 6, lane = t & 63;
  const int l16 = lane & 15, quad = lane >> 4;
  // ---- stage (sigmoid on the fly) ----
  if (t < 128) {
    const float* rq = P + (size_t)(q0 + t) * NP + h * 8;
    float4 a = *(const float4*)rq, b = *(const float4*)(rq + 4);
    uint4 w;
    w.x = f2bf(sigm(a.x)) | ((unsigned)f2bf(sigm(a.y)) << 16);
    w.y = f2bf(sigm(a.z)) | ((unsigned)f2bf(sigm(a.w)) << 16);
    w.z = f2bf(sigm(b.x)) | ((unsigned)f2bf(sigm(b.y)) << 16);
    w.w = f2bf(sigm(b.z)) | ((unsigned)f2bf(sigm(b.w)) << 16);
    *(uint4*)&Qlds[t * 8] = w;
  }
  {
    const float* rk = P + (size_t)(kb + t) * NP + 256 + h * 8;
    float4 k0 = *(const float4*)rk, k1 = *(const float4*)(rk + 4);
    float4 v0 = *(const float4*)(rk + 256), v1 = *(const float4*)(rk + 260);
    k0.x = sigm(k0.x); k0.y = sigm(k0.y); k0.z = sigm(k0.z); k0.w = sigm(k0.w);
    k1.x = sigm(k1.x); k1.y = sigm(k1.y); k1.z = sigm(k1.z); k1.w = sigm(k1.w);
    sk2[t] = (k0.x + k0.y + k0.z + k0.w + k1.x + k1.y + k1.z + k1.w) * 1.44269504f;
    uint4 w;
    w.x = f2bf(k0.x) | ((unsigned)f2bf(k0.y) << 16);
    w.y = f2bf(k0.z) | ((unsigned)f2bf(k0.w) << 16);
    w.z = f2bf(k1.x) | ((unsigned)f2bf(k1.y) << 16);
    w.w = f2bf(k1.z) | ((unsigned)f2bf(k1.w) << 16);
    *(uint4*)&Klds[t * 8] = w;
    Vt[0 * 264 + t] = f2bf(sigm(v0.x)); Vt[1 * 264 + t] = f2bf(sigm(v0.y));
    Vt[2 * 264 + t] = f2bf(sigm(v0.z)); Vt[3 * 264 + t] = f2bf(sigm(v0.w));
    Vt[4 * 264 + t] = f2bf(sigm(v1.x)); Vt[5 * 264 + t] = f2bf(sigm(v1.y));
    Vt[6 * 264 + t] = f2bf(sigm(v1.z)); Vt[7 * 264 + t] = f2bf(sigm(v1.w));
    Vt[8 * 264 + t] = 0x3F80;   // 1.0 bf16 -> row sums (l) in output col 8
#pragma unroll
    for (int d = 9; d < 16; d++) Vt[d * 264 + t] = 0;
  }
  __syncthreads();
  // ---- B-frags (Pq), fixed per wave's two q-tiles ----
  short8 bq[2];
#pragma unroll
  for (int i = 0; i < 2; i++) {
    short8 z = {0, 0, 0, 0, 0, 0, 0, 0};
    if (quad == 0) z = *(const short8*)&Qlds[((wave * 2 + i) * 16 + l16) * 8];
    bq[i] = z;
  }
  f32x4 O[2];
  O[0] = (f32x4){0.f, 0.f, 0.f, 0.f};
  O[1] = (f32x4){0.f, 0.f, 0.f, 0.f};
  const int nsl = needMask ? (m & 1) + 1 : 2;
  const int swz = (l16 >> 1) & 7;   // row-derived XOR for this lane's q-rows / write rows
  for (int sl = 0; sl < nsl; sl++) {
    const int ks = sl * 128;
    const bool dm = needMask && (sl == (m & 1));
    // ---- scores + exp -> P_lds ----
    for (int kt = 0; kt < 8; kt++) {
      short8 ak = {0, 0, 0, 0, 0, 0, 0, 0};
      if (quad == 0) ak = *(const short8*)&Klds[(ks + kt * 16 + l16) * 8];
      float4 s2 = *(const float4*)&sk2[ks + kt * 16 + quad * 4];
#pragma unroll
      for (int i = 0; i < 2; i++) {
        f32x4 c = __builtin_amdgcn_mfma_f32_16x16x32_bf16(
            ak, bq[i], (f32x4){0.f, 0.f, 0.f, 0.f}, 0, 0, 0);
        float e0 = exp2f(c[0] * 2.88539008f - s2.x);
        float e1 = exp2f(c[1] * 2.88539008f - s2.y);
        float e2 = exp2f(c[2] * 2.88539008f - s2.z);
        float e3 = exp2f(c[3] * 2.88539008f - s2.w);
        if (dm) {
          int q = q0 + (wave * 2 + i) * 16 + l16;
          int key = kb + ks + kt * 16 + quad * 4;
          e0 = (key + 0 <= q) ? e0 : 0.f;
          e1 = (key + 1 <= q) ? e1 : 0.f;
          e2 = (key + 2 <= q) ? e2 : 0.f;
          e3 = (key + 3 <= q) ? e3 : 0.f;
        }
        uint2 pk2;
        pk2.x = f2bf(e0) | ((unsigned)f2bf(e1) << 16);
        pk2.y = f2bf(e2) | ((unsigned)f2bf(e3) << 16);
        int row = (wave * 2 + i) * 16 + l16;
        int cb = 2 * kt + (quad >> 1);
        int pb = cb ^ swz;
        *(uint2*)&Plds[row * 128 + pb * 8 + (quad & 1) * 4] = pk2;
      }
    }
    // same-wave RAW on Plds rows (each wave owns its 32 q-rows) -> no barrier
    // ---- PV ----
#pragma unroll
    for (int kc4 = 0; kc4 < 4; kc4++) {
      short8 bv = *(const short8*)&Vt[l16 * 264 + ks + kc4 * 32 + quad * 8];
#pragma unroll
      for (int i = 0; i < 2; i++) {
        int row = (wave * 2 + i) * 16 + l16;
        int pb = (kc4 * 4 + quad) ^ swz;
        short8 ap = *(const short8*)&Plds[row * 128 + pb * 8];
        O[i] = __builtin_amdgcn_mfma_f32_16x16x32_bf16(ap, bv, O[i], 0, 0, 0);
      }
    }
  }
  // ---- write partials: O C-layout: row=q(quad*4+r), col=dim(l16); col8 = l ----
  if (l16 < 9) {
#pragma unroll
    for (int i = 0; i < 2; i++) {
      int qb = q0 + (wave * 2 + i) * 16 + quad * 4;
#pragma unroll
      for (int r = 0; r < 4; r++)
        Part[(((size_t)h * S + qb + r) * 8 + kc) * 12 + l16] = O[i][r];
    }
  }
}

// ---- merge partials, divide, v_emb interpolate, emit bf16 O2 [S x 256] ----
__global__ __launch_bounds__(256)
void attn_merge_k(const float* __restrict__ Part, const float* __restrict__ e0,
                  const float* __restrict__ e1, u16* __restrict__ O2) {
  const int q = blockIdx.x;
  const int t = threadIdx.x;         // t = h*8 + d
  const int d = t & 7;
  const int nch = (q >> 8) + 1;
  size_t base = ((size_t)(t >> 3) * S + q) * 8 * 12;
  float ov = 0.f, lv = 0.f;
  for (int kc = 0; kc < nch; kc++) {
    ov += Part[base + (size_t)kc * 12 + d];
    lv += Part[base + (size_t)kc * 12 + 8];
  }
  float outv = ov / lv;
  float r = e0[t] + (e1[t] - e0[t]) * outv;
  O2[(size_t)q * 256 + t] = f2bf(r);
}

extern "C" void kernel_launch(void* const* d_in, const int* in_sizes, int n_in,
                              void* d_out, int out_size, void* d_ws, size_t ws_size,
                              hipStream_t stream) {
  const float* hs = (const float*)d_in[0];
  const float* Wq = (const float*)d_in[1];
  const float* Wk = (const float*)d_in[2];
  const float* Wv = (const float*)d_in[3];
  const float* Wo = (const float*)d_in[4];
  const float* Wg = (const float*)d_in[5];
  const float* e0 = (const float*)d_in[6];
  const float* e1 = (const float*)d_in[7];
  float* out = (float*)d_out;
  char* ws = (char*)d_ws;
  // workspace layout (bytes)
  u16*   Abf  = (u16*)(ws + 0);          //  8,388,608  hs bf16 [2048 x 2048]
  u16*   Wt   = (u16*)(ws + 8388608);    // 11,534,336  [Wq|Wk|Wv|Wg]^T bf16 [2816 x 2048]
  u16*   Wot  = (u16*)(ws + 19922944);   //  1,048,576  Wo^T bf16 [2048 x 256]
  u16*   O2   = (u16*)(ws + 20971520);   //  1,048,576  attn out (emb-interp) bf16 [2048 x 256]
  float* P    = (float*)(ws + 22020096); //  6,291,456  hs@[Wq|Wk|Wv] logits fp32 [2048 x 768]
  float* Part = (float*)(ws + 28311552); // 25,165,824  partials [H][S][8 chunks][12]
  u16*   Wgt  = Wt + (size_t)768 * 2048; // gate weight transposed [2048 x 2048]

  trans_all_k<<<dim3(3584), 256, 0, stream>>>(Wq, Wk, Wv, Wg, Wo, hs, Wt, Wot, Abf);
  gemm_proj_k<<<dim3(NP / 64, S / 128), 256, 0, stream>>>(Abf, Wt, P, 2048, NP);
  attn_mfma_k<<<dim3(72, H), 256, 0, stream>>>(P, Part);
  attn_merge_k<<<dim3(S), 256, 0, stream>>>(Part, e0, e1, O2);
  gemm_outgate_k<<<dim3(DIM / 128, S / 128), 256, 0, stream>>>(O2, Wot, Abf, Wgt, out);
}

// Round 10
// 192.217 us; speedup vs baseline: 1.2123x; 1.1534x over previous
//
#include <hip/hip_runtime.h>

#define S 2048
#define DIM 2048
#define H 32
#define NB 2816   // 256(q) + 256(k) + 256(v) + 2048(gate) columns

using u16 = unsigned short;
using short8 = __attribute__((ext_vector_type(8))) short;
using f32x4 = __attribute__((ext_vector_type(4))) float;

__device__ __forceinline__ u16 f2bf(float x) {
  union { float f; unsigned u; } v; v.f = x;
  unsigned r = v.u + 0x7fffu + ((v.u >> 16) & 1u);
  return (u16)(r >> 16);
}
__device__ __forceinline__ float sigm(float x) { return 1.f / (1.f + __expf(-x)); }

// async global->LDS, 16B per lane; LDS dest must be wave-uniform base + lane*16
#define GLOAD_LDS16(g, l)                                                      \
  __builtin_amdgcn_global_load_lds(                                            \
      (const __attribute__((address_space(1))) unsigned*)(g),                  \
      (__attribute__((address_space(3))) unsigned*)(l), 16, 0, 0)

// ---- fused prep: 5 transposes (fp32 [KxN] -> bf16 [NxK]) + hs fp32->bf16 ----
// blocks 0..127 Wq | 128..255 Wk | 256..383 Wv | 384..1407 Wg | 1408..1535 Wo
// blocks 1536..3583: hs elementwise convert (2048 elems/block)
__global__ __launch_bounds__(256)
void trans_all_k(const float* __restrict__ Wq, const float* __restrict__ Wk,
                 const float* __restrict__ Wv, const float* __restrict__ Wg,
                 const float* __restrict__ Wo, const float* __restrict__ hs,
                 u16* __restrict__ Wt, u16* __restrict__ Wot, u16* __restrict__ Abf) {
  int b = blockIdx.x;
  const int t = threadIdx.x;
  if (b >= 1536) {  // hs fp32 -> bf16, fully coalesced
    int i = ((b - 1536) * 256 + t) * 8;
    float4 a = *(const float4*)(hs + i);
    float4 c = *(const float4*)(hs + i + 4);
    uint4 r;
    r.x = f2bf(a.x) | ((unsigned)f2bf(a.y) << 16);
    r.y = f2bf(a.z) | ((unsigned)f2bf(a.w) << 16);
    r.z = f2bf(c.x) | ((unsigned)f2bf(c.y) << 16);
    r.w = f2bf(c.z) | ((unsigned)f2bf(c.w) << 16);
    *(uint4*)(Abf + i) = r;
    return;
  }
  const float* in; u16* out; int K, N;
  if (b < 384) {
    K = 2048; N = 256;
    in = (b < 128) ? Wq : (b < 256) ? Wk : Wv;
    out = Wt + (size_t)(b >> 7) * 256 * 2048;
    b &= 127;
  } else if (b < 1408) {
    in = Wg; out = Wt + (size_t)768 * 2048; K = 2048; N = 2048; b -= 384;
  } else {
    in = Wo; out = Wot; K = 256; N = 2048; b -= 1408;
  }
  const int nbN = N >> 6;
  const int kb = (b / nbN) << 6, nb = (b % nbN) << 6;
  __shared__ float tile[64][65];   // 65-stride: write-phase reads 2-way (free)
  const int n4 = (t & 15) * 4;
#pragma unroll
  for (int p = 0; p < 4; p++) {
    int k = p * 16 + (t >> 4);
    float4 v = *(const float4*)(in + (size_t)(kb + k) * N + nb + n4);
    tile[k][n4] = v.x; tile[k][n4 + 1] = v.y; tile[k][n4 + 2] = v.z; tile[k][n4 + 3] = v.w;
  }
  __syncthreads();
  const int k8 = (t & 7) * 8;
#pragma unroll
  for (int p = 0; p < 2; p++) {
    int n = p * 32 + (t >> 3);
    uint4 w;
    w.x = f2bf(tile[k8 + 0][n]) | ((unsigned)f2bf(tile[k8 + 1][n]) << 16);
    w.y = f2bf(tile[k8 + 2][n]) | ((unsigned)f2bf(tile[k8 + 3][n]) << 16);
    w.z = f2bf(tile[k8 + 4][n]) | ((unsigned)f2bf(tile[k8 + 5][n]) << 16);
    w.w = f2bf(tile[k8 + 6][n]) | ((unsigned)f2bf(tile[k8 + 7][n]) << 16);
    *(uint4*)(out + (size_t)(nb + n) * K + kb + k8) = w;
  }
}

// ---- GEMM1: P = sigmoid(hs@[Wq|Wk|Wv|Wg]). 128x128 tile, grid 352, dbuf ----
__global__ __launch_bounds__(256)
void gemm128_k(const u16* __restrict__ A, const u16* __restrict__ Bt,
               float* __restrict__ C, int K, int ldc) {
  __shared__ u16 As[2][128][32];
  __shared__ u16 Bs[2][128][32];
  const int t = threadIdx.x;
  const int bm = blockIdx.y * 128, bn = blockIdx.x * 128;
  const int wave = t >> 6, lane = t & 63;
  const int wm = (wave >> 1) * 64, wn = (wave & 1) * 64;
  const int l16 = lane & 15, quad = lane >> 4;
  const int srow = t >> 2, scol = (t & 3) * 8;
  const u16* Ap = A + (size_t)(bm + srow) * K + scol;
  const u16* Bp = Bt + (size_t)(bn + srow) * K + scol;
  f32x4 acc[4][4];
#pragma unroll
  for (int i = 0; i < 4; i++)
#pragma unroll
    for (int j = 0; j < 4; j++) acc[i][j] = (f32x4){0.f, 0.f, 0.f, 0.f};
  GLOAD_LDS16(Ap, &As[0][srow][scol]);
  GLOAD_LDS16(Ap + (size_t)64 * K, &As[0][srow + 64][scol]);
  GLOAD_LDS16(Bp, &Bs[0][srow][scol]);
  GLOAD_LDS16(Bp + (size_t)64 * K, &Bs[0][srow + 64][scol]);
  for (int kk = 0; kk < K; kk += 32) {
    const int cur = (kk >> 5) & 1, nxt = cur ^ 1;
    __syncthreads();
    if (kk + 32 < K) {
      GLOAD_LDS16(Ap + kk + 32, &As[nxt][srow][scol]);
      GLOAD_LDS16(Ap + (size_t)64 * K + kk + 32, &As[nxt][srow + 64][scol]);
      GLOAD_LDS16(Bp + kk + 32, &Bs[nxt][srow][scol]);
      GLOAD_LDS16(Bp + (size_t)64 * K + kk + 32, &Bs[nxt][srow + 64][scol]);
    }
    short8 af[4], bf[4];
#pragma unroll
    for (int mt = 0; mt < 4; mt++) af[mt] = *(const short8*)&As[cur][wm + mt * 16 + l16][quad * 8];
#pragma unroll
    for (int nt = 0; nt < 4; nt++) bf[nt] = *(const short8*)&Bs[cur][wn + nt * 16 + l16][quad * 8];
#pragma unroll
    for (int mt = 0; mt < 4; mt++)
#pragma unroll
      for (int nt = 0; nt < 4; nt++)
        acc[mt][nt] = __builtin_amdgcn_mfma_f32_16x16x32_bf16(af[mt], bf[nt], acc[mt][nt], 0, 0, 0);
  }
  // C/D layout: col = lane&15, row = quad*4 + reg  [verified m89]
#pragma unroll
  for (int mt = 0; mt < 4; mt++)
#pragma unroll
    for (int nt = 0; nt < 4; nt++)
#pragma unroll
      for (int r = 0; r < 4; r++) {
        int m = bm + wm + mt * 16 + quad * 4 + r;
        int n = bn + wn + nt * 16 + l16;
        float v = acc[mt][nt][r];
        C[(size_t)m * ldc + n] = 1.f / (1.f + __expf(-v));
      }
}

// ---- GEMM2: out = (O2@Wot) * gate. 64x64 tile (grid 1024 = 4/CU), dbuf ----
__global__ __launch_bounds__(256)
void gemm64_k(const u16* __restrict__ A, const u16* __restrict__ Bt,
              float* __restrict__ C, const float* __restrict__ gate,
              int K, int ldc) {
  __shared__ u16 As[2][64][32];
  __shared__ u16 Bs[2][64][32];
  const int t = threadIdx.x;
  const int bm = blockIdx.y * 64, bn = blockIdx.x * 64;
  const int wave = t >> 6, lane = t & 63;
  const int wm = (wave >> 1) * 32, wn = (wave & 1) * 32;
  const int l16 = lane & 15, quad = lane >> 4;
  const int srow = t >> 2, scol = (t & 3) * 8;
  const u16* Ap = A + (size_t)(bm + srow) * K + scol;
  const u16* Bp = Bt + (size_t)(bn + srow) * K + scol;
  f32x4 acc[2][2];
#pragma unroll
  for (int i = 0; i < 2; i++)
#pragma unroll
    for (int j = 0; j < 2; j++) acc[i][j] = (f32x4){0.f, 0.f, 0.f, 0.f};
  GLOAD_LDS16(Ap, &As[0][srow][scol]);
  GLOAD_LDS16(Bp, &Bs[0][srow][scol]);
  for (int kk = 0; kk < K; kk += 32) {
    const int cur = (kk >> 5) & 1, nxt = cur ^ 1;
    __syncthreads();
    if (kk + 32 < K) {
      GLOAD_LDS16(Ap + kk + 32, &As[nxt][srow][scol]);
      GLOAD_LDS16(Bp + kk + 32, &Bs[nxt][srow][scol]);
    }
    short8 af[2], bf[2];
#pragma unroll
    for (int mt = 0; mt < 2; mt++) af[mt] = *(const short8*)&As[cur][wm + mt * 16 + l16][quad * 8];
#pragma unroll
    for (int nt = 0; nt < 2; nt++) bf[nt] = *(const short8*)&Bs[cur][wn + nt * 16 + l16][quad * 8];
#pragma unroll
    for (int mt = 0; mt < 2; mt++)
#pragma unroll
      for (int nt = 0; nt < 2; nt++)
        acc[mt][nt] = __builtin_amdgcn_mfma_f32_16x16x32_bf16(af[mt], bf[nt], acc[mt][nt], 0, 0, 0);
  }
#pragma unroll
  for (int mt = 0; mt < 2; mt++)
#pragma unroll
    for (int nt = 0; nt < 2; nt++)
#pragma unroll
      for (int r = 0; r < 4; r++) {
        int m = bm + wm + mt * 16 + quad * 4 + r;
        int n = bn + wn + nt * 16 + l16;
        float v = acc[mt][nt][r] * gate[(size_t)m * NB + n];
        C[(size_t)m * ldc + n] = v;
      }
}

// ---- MFMA attention partials: block = (head, q-tile 128, k-chunk 256) ----
// P holds sigmoided probabilities (fp32, stride NB).
// S^T scores: A=Pk (m=key), B=Pq (n=q) -> C row=key(quad*4+r), col=q(l16).
// e = exp2(dot*2/ln2 - sk*log2e); exp(-sq) cancels in o/l.
// PV: A = P (m=q), B = V^T rows (n=dim, row 8 = ones -> l in output col 8).
// P_lds XOR swizzle blk' = (col>>3) ^ ((row>>1)&7): 2-way (free) on write b64 + read b128.
__global__ __launch_bounds__(256)
void attn_mfma_k(const float* __restrict__ P, float* __restrict__ Part) {
  __shared__ u16 Plds[128 * 128];     // swizzled bf16 P slab [q 0..127][k-slab 0..127]
  __shared__ u16 Vt[16 * 264];        // V^T [dim 0..15][key 0..255], row8=1, rows9-15=0
  __shared__ u16 Klds[256 * 8];       // Pk bf16 [key][bit]
  __shared__ u16 Qlds[128 * 8];       // Pq bf16 [q][bit]
  __shared__ float sk2[256];          // sum(pk)*log2(e)
  const int h = blockIdx.y;
  int tau = blockIdx.x, m = 0;
  while (tau >= (m >> 1) + 1) { tau -= (m >> 1) + 1; m++; }
  const int kc = tau;
  const bool needMask = (kc == (m >> 1));
  const int q0 = m * 128, kb = kc * 256;
  const int t = threadIdx.x, wave = t >> 6, lane = t & 63;
  const int l16 = lane & 15, quad = lane >> 4;
  // ---- stage ----
  if (t < 128) {
    const float* rq = P + (size_t)(q0 + t) * NB + h * 8;
    float4 a = *(const float4*)rq, b = *(const float4*)(rq + 4);
    uint4 w;
    w.x = f2bf(a.x) | ((unsigned)f2bf(a.y) << 16);
    w.y = f2bf(a.z) | ((unsigned)f2bf(a.w) << 16);
    w.z = f2bf(b.x) | ((unsigned)f2bf(b.y) << 16);
    w.w = f2bf(b.z) | ((unsigned)f2bf(b.w) << 16);
    *(uint4*)&Qlds[t * 8] = w;
  }
  {
    const float* rk = P + (size_t)(kb + t) * NB + 256 + h * 8;
    float4 k0 = *(const float4*)rk, k1 = *(const float4*)(rk + 4);
    float4 v0 = *(const float4*)(rk + 256), v1 = *(const float4*)(rk + 260);
    sk2[t] = (k0.x + k0.y + k0.z + k0.w + k1.x + k1.y + k1.z + k1.w) * 1.44269504f;
    uint4 w;
    w.x = f2bf(k0.x) | ((unsigned)f2bf(k0.y) << 16);
    w.y = f2bf(k0.z) | ((unsigned)f2bf(k0.w) << 16);
    w.z = f2bf(k1.x) | ((unsigned)f2bf(k1.y) << 16);
    w.w = f2bf(k1.z) | ((unsigned)f2bf(k1.w) << 16);
    *(uint4*)&Klds[t * 8] = w;
    Vt[0 * 264 + t] = f2bf(v0.x); Vt[1 * 264 + t] = f2bf(v0.y);
    Vt[2 * 264 + t] = f2bf(v0.z); Vt[3 * 264 + t] = f2bf(v0.w);
    Vt[4 * 264 + t] = f2bf(v1.x); Vt[5 * 264 + t] = f2bf(v1.y);
    Vt[6 * 264 + t] = f2bf(v1.z); Vt[7 * 264 + t] = f2bf(v1.w);
    Vt[8 * 264 + t] = 0x3F80;   // 1.0 bf16 -> row sums (l) in output col 8
#pragma unroll
    for (int d = 9; d < 16; d++) Vt[d * 264 + t] = 0;
  }
  __syncthreads();
  // ---- B-frags (Pq), fixed per wave's two q-tiles ----
  short8 bq[2];
#pragma unroll
  for (int i = 0; i < 2; i++) {
    short8 z = {0, 0, 0, 0, 0, 0, 0, 0};
    if (quad == 0) z = *(const short8*)&Qlds[((wave * 2 + i) * 16 + l16) * 8];
    bq[i] = z;
  }
  f32x4 O[2];
  O[0] = (f32x4){0.f, 0.f, 0.f, 0.f};
  O[1] = (f32x4){0.f, 0.f, 0.f, 0.f};
  const int nsl = needMask ? (m & 1) + 1 : 2;
  const int swz = (l16 >> 1) & 7;   // row-derived XOR for this lane's q-rows / write rows
  for (int sl = 0; sl < nsl; sl++) {
    const int ks = sl * 128;
    const bool dm = needMask && (sl == (m & 1));
    // ---- scores + exp -> P_lds ----
    for (int kt = 0; kt < 8; kt++) {
      short8 ak = {0, 0, 0, 0, 0, 0, 0, 0};
      if (quad == 0) ak = *(const short8*)&Klds[(ks + kt * 16 + l16) * 8];
      float4 s2 = *(const float4*)&sk2[ks + kt * 16 + quad * 4];
#pragma unroll
      for (int i = 0; i < 2; i++) {
        f32x4 c = __builtin_amdgcn_mfma_f32_16x16x32_bf16(
            ak, bq[i], (f32x4){0.f, 0.f, 0.f, 0.f}, 0, 0, 0);
        float e0 = exp2f(c[0] * 2.88539008f - s2.x);
        float e1 = exp2f(c[1] * 2.88539008f - s2.y);
        float e2 = exp2f(c[2] * 2.88539008f - s2.z);
        float e3 = exp2f(c[3] * 2.88539008f - s2.w);
        if (dm) {
          int q = q0 + (wave * 2 + i) * 16 + l16;
          int key = kb + ks + kt * 16 + quad * 4;
          e0 = (key + 0 <= q) ? e0 : 0.f;
          e1 = (key + 1 <= q) ? e1 : 0.f;
          e2 = (key + 2 <= q) ? e2 : 0.f;
          e3 = (key + 3 <= q) ? e3 : 0.f;
        }
        uint2 pk2;
        pk2.x = f2bf(e0) | ((unsigned)f2bf(e1) << 16);
        pk2.y = f2bf(e2) | ((unsigned)f2bf(e3) << 16);
        int row = (wave * 2 + i) * 16 + l16;
        int cb = 2 * kt + (quad >> 1);
        int pb = cb ^ swz;
        *(uint2*)&Plds[row * 128 + pb * 8 + (quad & 1) * 4] = pk2;
      }
    }
    // same-wave RAW on Plds rows (each wave owns its 32 q-rows) -> no barrier
    // ---- PV ----
#pragma unroll
    for (int kc4 = 0; kc4 < 4; kc4++) {
      short8 bv = *(const short8*)&Vt[l16 * 264 + ks + kc4 * 32 + quad * 8];
#pragma unroll
      for (int i = 0; i < 2; i++) {
        int row = (wave * 2 + i) * 16 + l16;
        int pb = (kc4 * 4 + quad) ^ swz;
        short8 ap = *(const short8*)&Plds[row * 128 + pb * 8];
        O[i] = __builtin_amdgcn_mfma_f32_16x16x32_bf16(ap, bv, O[i], 0, 0, 0);
      }
    }
  }
  // ---- write partials: O C-layout: row=q(quad*4+r), col=dim(l16); col8 = l ----
  if (l16 < 9) {
#pragma unroll
    for (int i = 0; i < 2; i++) {
      int qb = q0 + (wave * 2 + i) * 16 + quad * 4;
#pragma unroll
      for (int r = 0; r < 4; r++)
        Part[(((size_t)h * S + qb + r) * 8 + kc) * 12 + l16] = O[i][r];
    }
  }
}

// ---- merge partials, divide, v_emb interpolate, emit bf16 O2 [S x 256] ----
__global__ __launch_bounds__(256)
void attn_merge_k(const float* __restrict__ Part, const float* __restrict__ e0,
                  const float* __restrict__ e1, u16* __restrict__ O2) {
  const int q = blockIdx.x;
  const int t = threadIdx.x;         // t = h*8 + d
  const int d = t & 7;
  const int nch = (q >> 8) + 1;
  size_t base = ((size_t)(t >> 3) * S + q) * 8 * 12;
  float ov = 0.f, lv = 0.f;
  for (int kc = 0; kc < nch; kc++) {
    ov += Part[base + (size_t)kc * 12 + d];
    lv += Part[base + (size_t)kc * 12 + 8];
  }
  float outv = ov / lv;
  float r = e0[t] + (e1[t] - e0[t]) * outv;
  O2[(size_t)q * 256 + t] = f2bf(r);
}

extern "C" void kernel_launch(void* const* d_in, const int* in_sizes, int n_in,
                              void* d_out, int out_size, void* d_ws, size_t ws_size,
                              hipStream_t stream) {
  const float* hs = (const float*)d_in[0];
  const float* Wq = (const float*)d_in[1];
  const float* Wk = (const float*)d_in[2];
  const float* Wv = (const float*)d_in[3];
  const float* Wo = (const float*)d_in[4];
  const float* Wg = (const float*)d_in[5];
  const float* e0 = (const float*)d_in[6];
  const float* e1 = (const float*)d_in[7];
  float* out = (float*)d_out;
  char* ws = (char*)d_ws;
  // workspace layout (bytes)
  u16*   Abf  = (u16*)(ws + 0);          //  8,388,608  hs bf16 [2048 x 2048]
  u16*   Wt   = (u16*)(ws + 8388608);    // 11,534,336  [Wq|Wk|Wv|Wg]^T bf16 [2816 x 2048]
  u16*   Wot  = (u16*)(ws + 19922944);   //  1,048,576  Wo^T bf16 [2048 x 256]
  u16*   O2   = (u16*)(ws + 20971520);   //  1,048,576  attn out (emb-interp) bf16 [2048 x 256]
  float* P    = (float*)(ws + 22020096); // 23,068,672  sigmoid(hs@[Wq|Wk|Wv|Wg]) fp32 [2048 x 2816]
  float* Part = (float*)(ws + 45088768); // 25,165,824  partials [H][S][8 chunks][12]

  trans_all_k<<<dim3(3584), 256, 0, stream>>>(Wq, Wk, Wv, Wg, Wo, hs, Wt, Wot, Abf);
  gemm128_k<<<dim3(NB / 128, S / 128), 256, 0, stream>>>(Abf, Wt, P, 2048, NB);
  attn_mfma_k<<<dim3(72, H), 256, 0, stream>>>(P, Part);
  attn_merge_k<<<dim3(S), 256, 0, stream>>>(Part, e0, e1, O2);
  gemm64_k<<<dim3(DIM / 64, S / 64), 256, 0, stream>>>(O2, Wot, out, P + 768, 256, DIM);
}